// Round 6
// baseline (597.715 us; speedup 1.0000x reference)
//
#include <hip/hip_runtime.h>

#define BS 512
#define SL 1024
#define NC 64

// ---------------------------------------------------------------------------
// Cross-lane primitives (wave64)
// ---------------------------------------------------------------------------
template <int CTRL>
__device__ __forceinline__ float dppf(float x) {
    return __int_as_float(__builtin_amdgcn_mov_dpp(__float_as_int(x), CTRL, 0xF, 0xF, true));
}
__device__ __forceinline__ float rflf(float x) {
    return __int_as_float(__builtin_amdgcn_readfirstlane(__float_as_int(x)));
}

__device__ __forceinline__ void halfswap32(float x, float& r0, float& r1) {
#if __has_builtin(__builtin_amdgcn_permlane32_swap)
    auto r = __builtin_amdgcn_permlane32_swap(__float_as_int(x), __float_as_int(x), false, false);
    r0 = __int_as_float(r[0]); r1 = __int_as_float(r[1]);
#else
    float w = __shfl_xor(x, 32, 64);
    bool up = (threadIdx.x & 32) != 0;
    r0 = up ? w : x;
    r1 = up ? x : w;
#endif
}
__device__ __forceinline__ void halfswap16(float x, float& r0, float& r1) {
#if __has_builtin(__builtin_amdgcn_permlane16_swap)
    auto r = __builtin_amdgcn_permlane16_swap(__float_as_int(x), __float_as_int(x), false, false);
    r0 = __int_as_float(r[0]); r1 = __int_as_float(r[1]);
#else
    float w = __int_as_float(__builtin_amdgcn_ds_swizzle(__float_as_int(x), 0x401F)); // xor16
    bool up = (threadIdx.x & 16) != 0;
    r0 = up ? w : x;
    r1 = up ? x : w;
#endif
}

__device__ __forceinline__ float wave_sum(float x) {
    x += dppf<0xB1>(x);   // xor1
    x += dppf<0x4E>(x);   // xor2
    x += dppf<0x141>(x);  // xor7 (row_half_mirror)
    x += dppf<0x140>(x);  // xor15 (row_mirror)
    float a, c;
    halfswap16(x, a, c); x = a + c;
    halfswap32(x, a, c); x = a + c;
    return x;
}

// ---------------------------------------------------------------------------
// Kernel 1: out[0] = 0 (loss acc), out[1..4096] = transitions copy
// ---------------------------------------------------------------------------
__global__ __launch_bounds__(256) void crf_init_out(const float* __restrict__ trans,
                                                    float* __restrict__ out) {
    int idx = blockIdx.x * 256 + threadIdx.x;
    if (idx == 0) out[0] = 0.0f;
    if (idx < NC * NC) out[1 + idx] = trans[idx];
}

// ---------------------------------------------------------------------------
// Kernel 2: unary + binary score sums (fully parallel). Adds -(u+b)/BS to out.
// ---------------------------------------------------------------------------
__global__ __launch_bounds__(256) void crf_ub(const float* __restrict__ inputs,
                                              const int* __restrict__ masks,
                                              const int* __restrict__ tags,
                                              const float* __restrict__ trans,
                                              float* __restrict__ out) {
    const int b = blockIdx.x;
    const int tid = threadIdx.x;
    const int* tg = tags + (size_t)b * SL;
    const int* mk = masks + (size_t)b * SL;
    const float* xb = inputs + (size_t)b * SL * NC;

    float acc = 0.0f;
    const int t0 = tid * 4;
    int tprev = (t0 > 0) ? tg[t0 - 1] : 0;
#pragma unroll
    for (int j = 0; j < 4; ++j) {
        int t = t0 + j;
        int tgt = tg[t];
        if (mk[t] == 0) {
            acc += xb[(size_t)t * NC + tgt];                 // unary
            if (t > 0) acc += trans[tprev * NC + tgt];       // binary
        }
        tprev = tgt;
    }

    acc = wave_sum(acc);
    __shared__ float r[4];
    if ((tid & 63) == 0) r[tid >> 6] = acc;
    __syncthreads();
    if (tid == 0) atomicAdd(out, -(r[0] + r[1] + r[2] + r[3]) * (1.0f / BS));
}

// ---------------------------------------------------------------------------
// Kernel 3: forward recurrence only. One wave per batch, lane c owns class c.
//   q'_c = (sum_i q_i * E[i][c]) * exp(x_c) / m,   base += log(m)
// E = exp(T) held in 64 VGPRs (pinned); in-register DPP all-gather, zero LDS.
// Adds +log_norm/BS to out.
// ---------------------------------------------------------------------------
__global__ __launch_bounds__(64) __attribute__((amdgpu_waves_per_eu(1)))
void crf_fwd(const float* __restrict__ inputs,
             const int* __restrict__ masks,
             const float* __restrict__ trans,
             float* __restrict__ out) {
    const int b = blockIdx.x;
    const int lane = threadIdx.x;
    const float* __restrict__ xp = inputs + (size_t)b * SL * NC;

    // ---- len = lengths[b] via ballot popcount (masks monotone)
    int len = 0;
#pragma unroll
    for (int k = 0; k < SL / NC; ++k) {
        unsigned long long bal = __ballot(masks[(size_t)b * SL + k * NC + lane] == 0);
        len += __popcll(bal);
    }

    // ---- probe the halfswap half-assignment convention
    int B[4];
    {
        float pf = __int_as_float(lane);
        float p0, p1, a0, a1, c0, c1;
        halfswap32(pf, p0, p1);
        halfswap16(p0, a0, a1);
        halfswap16(p1, c0, c1);
        B[0] = __builtin_amdgcn_readfirstlane(__float_as_int(a0));
        B[1] = __builtin_amdgcn_readfirstlane(__float_as_int(a1));
        B[2] = __builtin_amdgcn_readfirstlane(__float_as_int(c0));
        B[3] = __builtin_amdgcn_readfirstlane(__float_as_int(c1));
    }

    // ---- E registers matched to gather layout; pinned to block remat/spill
    float E[64];
#pragma unroll
    for (int f = 0; f < 4; ++f) {
#pragma unroll
        for (int m = 0; m < 16; ++m) {
            int row = B[f] + ((lane ^ m) & 15);
            E[f * 16 + m] = __expf(trans[row * NC + lane]);
        }
    }
#pragma unroll
    for (int i = 0; i < 64; ++i) {
        asm volatile("" : "+v"(E[i]));   // pin: keep resident in a VGPR
    }

    // ---- t = 0 init
    float x0 = xp[lane];
    float base = rflf(x0);
    float q = __expf(x0 - base);

    // pipeline: xn1 = x[t+1], xn2 = x[t+2]; ex = exp(x[t])
    float ex  = __expf(xp[NC + lane]);        // exp for t=1
    float xn1 = xp[2 * NC + lane];            // t+1 input for exp (t=1 view)
    float xn2 = xp[3 * NC + lane];            // len>=512 so always valid

    for (int t = 1; t < len; ++t) {
        // --- off-chain: prefetch x[t+3], next exp, rescale factors
        int t3 = t + 3; if (t3 > SL - 1) t3 = SL - 1;
        float xnew = xp[(size_t)t3 * NC + lane];
        float exn = __expf(xn1);

        float m  = rflf(q);
        float rm = __builtin_amdgcn_rcpf(m);
        float ex_eff = ex * rm;
        base += __logf(m);

        // --- chain: family-blocked gather + matvec (short live ranges)
        float h0, h1, h2, h3, u0, u1;
        halfswap32(q, u0, u1);
        halfswap16(u0, h0, h1);
        halfswap16(u1, h2, h3);
        float a0 = 0.f, a1 = 0.f, a2 = 0.f, a3 = 0.f;
        float a4 = 0.f, a5 = 0.f, a6 = 0.f, a7 = 0.f;
#pragma unroll
        for (int f = 0; f < 4; ++f) {
            float v0 = (f == 0) ? h0 : (f == 1) ? h1 : (f == 2) ? h2 : h3;
            float v1  = dppf<0xB1>(v0);    // ^1
            float v2  = dppf<0x4E>(v0);    // ^2
            float v3  = dppf<0x4E>(v1);    // ^3
            float v7  = dppf<0x141>(v0);   // ^7
            float v6  = dppf<0x141>(v1);   // ^6
            float v5  = dppf<0x141>(v2);   // ^5
            float v4  = dppf<0x141>(v3);   // ^4
            a0 = fmaf(v0, E[f * 16 + 0], a0);
            a1 = fmaf(v1, E[f * 16 + 1], a1);
            a2 = fmaf(v2, E[f * 16 + 2], a2);
            a3 = fmaf(v3, E[f * 16 + 3], a3);
            float v15 = dppf<0x140>(v0);   // ^15
            float v14 = dppf<0x140>(v1);   // ^14
            float v13 = dppf<0x140>(v2);   // ^13
            float v12 = dppf<0x140>(v3);   // ^12
            a4 = fmaf(v4, E[f * 16 + 4], a4);
            a5 = fmaf(v5, E[f * 16 + 5], a5);
            a6 = fmaf(v6, E[f * 16 + 6], a6);
            a7 = fmaf(v7, E[f * 16 + 7], a7);
            float v11 = dppf<0x140>(v4);   // ^11
            float v10 = dppf<0x140>(v5);   // ^10
            float v9  = dppf<0x140>(v6);   // ^9
            float v8  = dppf<0x140>(v7);   // ^8
            a0 = fmaf(v8,  E[f * 16 + 8],  a0);
            a1 = fmaf(v9,  E[f * 16 + 9],  a1);
            a2 = fmaf(v10, E[f * 16 + 10], a2);
            a3 = fmaf(v11, E[f * 16 + 11], a3);
            a4 = fmaf(v12, E[f * 16 + 12], a4);
            a5 = fmaf(v13, E[f * 16 + 13], a5);
            a6 = fmaf(v14, E[f * 16 + 14], a6);
            a7 = fmaf(v15, E[f * 16 + 15], a7);
        }
        float s = ((a0 + a1) + (a2 + a3)) + ((a4 + a5) + (a6 + a7));
        q = s * ex_eff;

        // rotate pipeline
        ex = exn; xn1 = xn2; xn2 = xnew;
    }

    // ---- log_norm = base + log(sum_c q_c)
    float qsum = wave_sum(q);
    float log_norm = base + __logf(qsum);
    if (lane == 0) atomicAdd(out, log_norm * (1.0f / BS));
}

// ---------------------------------------------------------------------------
extern "C" void kernel_launch(void* const* d_in, const int* in_sizes, int n_in,
                              void* d_out, int out_size, void* d_ws, size_t ws_size,
                              hipStream_t stream) {
    const float* inputs = (const float*)d_in[0];
    const int*   masks  = (const int*)d_in[1];
    const int*   tags   = (const int*)d_in[2];
    const float* trans  = (const float*)d_in[3];
    float* out = (float*)d_out;

    crf_init_out<<<(1 + NC * NC + 255) / 256, 256, 0, stream>>>(trans, out);
    crf_ub<<<BS, 256, 0, stream>>>(inputs, masks, tags, trans, out);
    crf_fwd<<<BS, 64, 0, stream>>>(inputs, masks, trans, out);
}